// Round 6
// baseline (302.408 us; speedup 1.0000x reference)
//
#include <hip/hip_runtime.h>
#include <hip/hip_bf16.h>

typedef __attribute__((ext_vector_type(8))) short bf16x8;
typedef __attribute__((ext_vector_type(4))) float f32x4;
typedef __attribute__((ext_vector_type(4))) short short4v;

#define D128 128
#define IMG_SHORTS 16384          // one W frag-image: 32 frags x 64 lanes x 8 bf16 = 32 KB
#define H_OFF 65536               // H2 starts at 128 KiB into d_ws (in shorts)

__device__ __forceinline__ short f2bf(float f) {
    union { float f; unsigned u; } v; v.f = f;
    unsigned r = (v.u + 0x7FFFu + ((v.u >> 16) & 1u)) >> 16;  // RNE
    return (short)r;
}

__device__ __forceinline__ short f2bf_h(float f) {
    __hip_bfloat16 h = __float2bfloat16(f);
    short s;
    __builtin_memcpy(&s, &h, sizeof(short));
    return s;
}

__device__ __forceinline__ bf16x8 pack8(float4 a, float4 b) {
    bf16x8 r;
    r[0] = f2bf_h(a.x); r[1] = f2bf_h(a.y); r[2] = f2bf_h(a.z); r[3] = f2bf_h(a.w);
    r[4] = f2bf_h(b.x); r[5] = f2bf_h(b.y); r[6] = f2bf_h(b.z); r[7] = f2bf_h(b.w);
    return r;
}

__device__ __forceinline__ float bf2f(short s) {
    unsigned u = ((unsigned)(unsigned short)s) << 16;
    float f; __builtin_memcpy(&f, &u, 4);
    return f;
}

__device__ __forceinline__ void gload_lds16(const short* g, short* l) {
    __builtin_amdgcn_global_load_lds(
        (const __attribute__((address_space(1))) unsigned int*)(const void*)g,
        (__attribute__((address_space(3))) unsigned int*)(void*)l, 16, 0, 0);
}

// W (3*128 x 128 fp32 row-major) -> 3 A-operand fragment images (src,dst,e):
// img[c][frag=mt*4+ks][lane][j] = W[c*128 + ks*32 + (lane>>4)*8 + j][mt*16 + (lane&15)]
__global__ __launch_bounds__(256) void wt_kernel(const float* __restrict__ W,
                                                 short* __restrict__ Wimg) {
    const int c    = blockIdx.x >> 3;
    const int frag = (blockIdx.x & 7) * 4 + (threadIdx.x >> 6);
    const int lane = threadIdx.x & 63;
    const int mt = frag >> 2, ks = frag & 3;
    const int m  = mt * 16 + (lane & 15);
    const int k0 = ks * 32 + (lane >> 4) * 8;
    bf16x8 v;
#pragma unroll
    for (int j = 0; j < 8; ++j)
        v[j] = f2bf(W[(size_t)(c * 128 + k0 + j) * D128 + m]);
    *reinterpret_cast<bf16x8*>(
        &Wimg[((size_t)c * 32 + frag) * 64 * 8 + (size_t)lane * 8]) = v;
}

// Dense: H2[n][c][lhi][mt][0..3] = (x[n] @ W_c)[mt*16 + lhi*4 + j]   (bf16)
// Fragment-major layout so eb's gathers are 64B-contiguous per lane.
// 1024 thr = 16 waves; 256 rows/block; 64 KB LDS -> 2 blocks/CU.
__global__ __launch_bounds__(1024, 8) void ha_kernel(const float* __restrict__ x,
                                                     const short* __restrict__ Wimg,
                                                     short* __restrict__ H,
                                                     int Nrows) {
    __shared__ short Ws[2 * IMG_SHORTS];   // 64 KB: src + dst images

    const int tid  = threadIdx.x;
    const int lane = tid & 63;
    const int w    = tid >> 6;            // 0..15
    const int lhi  = lane >> 4;
    const int rn   = blockIdx.x * 256 + w * 16 + (lane & 15);
    const bool valid = rn < Nrows;
    const int  rl  = valid ? rn : (Nrows - 1);

    // stage both W images: 4096 x 16B units, 4 per thread, linear both sides
#pragma unroll
    for (int jj = 0; jj < 4; ++jj) {
        int unit = jj * 1024 + tid;
        gload_lds16(Wimg + (size_t)unit * 8, &Ws[unit * 8]);
    }
    asm volatile("" ::: "memory");

    const float* px = x + (size_t)rl * D128;
    float4 ev[8];
#pragma unroll
    for (int ks = 0; ks < 4; ++ks) {
        ev[2 * ks]     = reinterpret_cast<const float4*>(px + ks * 32 + lhi * 8)[0];
        ev[2 * ks + 1] = reinterpret_cast<const float4*>(px + ks * 32 + lhi * 8)[1];
    }
    asm volatile("" ::: "memory");
    asm volatile("s_waitcnt vmcnt(8)" ::: "memory");   // drain stage; x loads fly
    __builtin_amdgcn_s_barrier();

    bf16x8 bx[4];
#pragma unroll
    for (int ks = 0; ks < 4; ++ks) bx[ks] = pack8(ev[2 * ks], ev[2 * ks + 1]);

    f32x4 acc[16];
#pragma unroll
    for (int i = 0; i < 16; ++i) acc[i] = (f32x4){0.f, 0.f, 0.f, 0.f};

#pragma unroll
    for (int c = 0; c < 2; ++c)
#pragma unroll
        for (int ks = 0; ks < 4; ++ks)
#pragma unroll
            for (int mt = 0; mt < 8; ++mt) {
                bf16x8 a = *reinterpret_cast<const bf16x8*>(
                    &Ws[((c * 32 + mt * 4 + ks) * 64 + lane) * 8]);
                acc[c * 8 + mt] = __builtin_amdgcn_mfma_f32_16x16x32_bf16(
                    a, bx[ks], acc[c * 8 + mt], 0, 0, 0);
            }

    if (valid) {
        // H2 short offset: rn*256 + c*128 + lhi*32 + mt*4 + j
        short* ph = H + (size_t)rn * 256 + lhi * 32;
#pragma unroll
        for (int i = 0; i < 16; ++i) {
            short4v sv;
            sv[0] = f2bf_h(acc[i][0]); sv[1] = f2bf_h(acc[i][1]);
            sv[2] = f2bf_h(acc[i][2]); sv[3] = f2bf_h(acc[i][3]);
            *reinterpret_cast<short4v*>(ph + (i >> 3) * 128 + (i & 7) * 4) = sv;
        }
    }
}

// Main: out[r] = e[r] @ W_e + H2[src[r]].srchalf + H2[dst[r]].dsthalf
// 512 thr = 8 waves; 128 rows/block; lane owns row rn; gathers 64B-contiguous.
__global__ __launch_bounds__(512, 8) void eb_kernel(const float* __restrict__ e,
                                                    const short* __restrict__ Wimg,
                                                    const short* __restrict__ H,
                                                    const int*  __restrict__ src_idx,
                                                    const int*  __restrict__ dst_idx,
                                                    float* __restrict__ out) {
    __shared__ short Ws[IMG_SHORTS];   // 32 KB: W_e image

    const int tid  = threadIdx.x;
    const int lane = tid & 63;
    const int w    = tid >> 6;
    const int lhi  = lane >> 4;
    const int rn   = blockIdx.x * 128 + w * 16 + (lane & 15);

    // idx first (gather addresses depend on them)
    const int si = src_idx[rn];
    const int di = dst_idx[rn];
    asm volatile("" ::: "memory");

    // stage W_e image: 2048 x 16B units, 4 per thread
#pragma unroll
    for (int jj = 0; jj < 4; ++jj) {
        int unit = jj * 512 + tid;
        gload_lds16(Wimg + (size_t)unit * 8, &Ws[unit * 8]);
    }
    asm volatile("" ::: "memory");

    // e row loads (independent of idx): full 128B line per row per ks
    const float* pe = e + (size_t)rn * D128;
    float4 ev[8];
#pragma unroll
    for (int ks = 0; ks < 4; ++ks) {
        ev[2 * ks]     = reinterpret_cast<const float4*>(pe + ks * 32 + lhi * 8)[0];
        ev[2 * ks + 1] = reinterpret_cast<const float4*>(pe + ks * 32 + lhi * 8)[1];
    }
    asm volatile("" ::: "memory");

    // H2 gathers: 64B contiguous per row-half per lane (4 x dwordx4 each)
    const short* phs = H + (size_t)si * 256 + lhi * 32;         // src half
    const short* phd = H + (size_t)di * 256 + 128 + lhi * 32;   // dst half
    bf16x8 hs8[4], hd8[4];
#pragma unroll
    for (int q = 0; q < 4; ++q) {
        hs8[q] = reinterpret_cast<const bf16x8*>(phs)[q];
        hd8[q] = reinterpret_cast<const bf16x8*>(phd)[q];
    }
    asm volatile("" ::: "memory");
    // outstanding after idx drained: 4 stage + 8 e + 8 H = 20; drain stage only.
    asm volatile("s_waitcnt vmcnt(16)" ::: "memory");
    __builtin_amdgcn_s_barrier();

    bf16x8 bx[4];
#pragma unroll
    for (int ks = 0; ks < 4; ++ks) bx[ks] = pack8(ev[2 * ks], ev[2 * ks + 1]);

    f32x4 acc[8];
#pragma unroll
    for (int mt = 0; mt < 8; ++mt) acc[mt] = (f32x4){0.f, 0.f, 0.f, 0.f};

#pragma unroll
    for (int ks = 0; ks < 4; ++ks)
#pragma unroll
        for (int mt = 0; mt < 8; ++mt) {
            bf16x8 a = *reinterpret_cast<const bf16x8*>(
                &Ws[((mt * 4 + ks) * 64 + lane) * 8]);
            acc[mt] = __builtin_amdgcn_mfma_f32_16x16x32_bf16(a, bx[ks], acc[mt], 0, 0, 0);
        }

    float* po = out + (size_t)rn * D128 + lhi * 4;
#pragma unroll
    for (int mt = 0; mt < 8; ++mt) {
        const int q = mt >> 1, h = (mt & 1) * 4;
        f32x4 r = acc[mt];
        r[0] += bf2f(hs8[q][h + 0]) + bf2f(hd8[q][h + 0]);
        r[1] += bf2f(hs8[q][h + 1]) + bf2f(hd8[q][h + 1]);
        r[2] += bf2f(hs8[q][h + 2]) + bf2f(hd8[q][h + 2]);
        r[3] += bf2f(hs8[q][h + 3]) + bf2f(hd8[q][h + 3]);
        *reinterpret_cast<float4*>(po + mt * 16) = *(float4*)&r;
    }
}

extern "C" void kernel_launch(void* const* d_in, const int* in_sizes, int n_in,
                              void* d_out, int out_size, void* d_ws, size_t ws_size,
                              hipStream_t stream) {
    const float* x = (const float*)d_in[0];
    const float* e = (const float*)d_in[1];
    const float* W = (const float*)d_in[2];
    const int* src = (const int*)d_in[3];
    const int* dst = (const int*)d_in[4];
    float* out = (float*)d_out;

    short* Wimg = (short*)d_ws;                 // 3 x 32 KB frag images
    short* H    = (short*)d_ws + H_OFF;         // 100000 x 256 bf16 = 51.2 MB

    const int N = in_sizes[0] / D128;           // 100000
    const int E = in_sizes[3];                  // 400000

    wt_kernel<<<24, 256, 0, stream>>>(W, Wimg);
    ha_kernel<<<(N + 255) / 256, 1024, 0, stream>>>(x, Wimg, H, N);
    eb_kernel<<<E / 128, 512, 0, stream>>>(e, Wimg + 2 * IMG_SHORTS, H, src, dst, out);
}

// Round 7
// 151.265 us; speedup vs baseline: 1.9992x; 1.9992x over previous
//
#include <hip/hip_runtime.h>
#include <hip/hip_bf16.h>

typedef __attribute__((ext_vector_type(8))) short bf16x8;
typedef __attribute__((ext_vector_type(4))) float f32x4;

#define D128 128
#define IMG_SHORTS 16384          // one W frag-image: 32 frags x 64 lanes x 8 bf16 = 32 KB
#define XB_OFF 65536              // xb at 128 KiB into d_ws (in shorts)

__device__ __forceinline__ short f2bf(float f) {
    union { float f; unsigned u; } v; v.f = f;
    unsigned r = (v.u + 0x7FFFu + ((v.u >> 16) & 1u)) >> 16;  // RNE
    return (short)r;
}

__device__ __forceinline__ short f2bf_h(float f) {
    __hip_bfloat16 h = __float2bfloat16(f);
    short s;
    __builtin_memcpy(&s, &h, sizeof(short));
    return s;
}

__device__ __forceinline__ bf16x8 pack8(float4 a, float4 b) {
    bf16x8 r;
    r[0] = f2bf_h(a.x); r[1] = f2bf_h(a.y); r[2] = f2bf_h(a.z); r[3] = f2bf_h(a.w);
    r[4] = f2bf_h(b.x); r[5] = f2bf_h(b.y); r[6] = f2bf_h(b.z); r[7] = f2bf_h(b.w);
    return r;
}

__device__ __forceinline__ void gload_lds16(const short* g, short* l) {
    __builtin_amdgcn_global_load_lds(
        (const __attribute__((address_space(1))) unsigned int*)(const void*)g,
        (__attribute__((address_space(3))) unsigned int*)(void*)l, 16, 0, 0);
}

// W (3*128 x 128 fp32 row-major) -> 3 A-operand fragment images (src,dst,e):
// img[c][frag=mt*4+ks][lane][j] = W[c*128 + ks*32 + (lane>>4)*8 + j][mt*16 + (lane&15)]
__global__ __launch_bounds__(256) void wt_kernel(const float* __restrict__ W,
                                                 short* __restrict__ Wimg) {
    const int c    = blockIdx.x >> 3;
    const int frag = (blockIdx.x & 7) * 4 + (threadIdx.x >> 6);
    const int lane = threadIdx.x & 63;
    const int mt = frag >> 2, ks = frag & 3;
    const int m  = mt * 16 + (lane & 15);
    const int k0 = ks * 32 + (lane >> 4) * 8;
    bf16x8 v;
#pragma unroll
    for (int j = 0; j < 8; ++j)
        v[j] = f2bf(W[(size_t)(c * 128 + k0 + j) * D128 + m]);
    *reinterpret_cast<bf16x8*>(
        &Wimg[((size_t)c * 32 + frag) * 64 * 8 + (size_t)lane * 8]) = v;
}

// x (fp32) -> xb (bf16), 8 elems/thread.
__global__ __launch_bounds__(256) void xb_kernel(const float* __restrict__ x,
                                                 short* __restrict__ xb) {
    const size_t i = ((size_t)blockIdx.x * 256 + threadIdx.x) * 8;
    float4 v0 = reinterpret_cast<const float4*>(x + i)[0];
    float4 v1 = reinterpret_cast<const float4*>(x + i)[1];
    *reinterpret_cast<bf16x8*>(xb + i) = pack8(v0, v1);
}

// Fused gather-GEMM, single 32KB W buffer restaged per chunk (3 phases):
// out[r] = [x[src[r]] | x[dst[r]] | e[r]] @ W   (bf16 MFMA, fp32 acc)
// 512 thr = 8 waves; lane owns output row rn = r0 + w*16 + (lane&15);
// swapped operands: A = W frag image (LDS), B = gathered row frags (regs).
__global__ __launch_bounds__(512, 4) void fused_kernel(
        const short* __restrict__ xb,
        const float* __restrict__ e,
        const short* __restrict__ Wimg,
        const int*  __restrict__ src_idx,
        const int*  __restrict__ dst_idx,
        float* __restrict__ out)
{
    __shared__ short Ws[IMG_SHORTS];   // 32 KB, one chunk image at a time

    const int tid  = threadIdx.x;
    const int lane = tid & 63;
    const int w    = tid >> 6;
    const int lhi  = lane >> 4;
    const int rn   = blockIdx.x * D128 + w * 16 + (lane & 15);

    // ---- idx (oldest vm ops) ----
    const int si = src_idx[rn];
    const int di = dst_idx[rn];
    asm volatile("" ::: "memory");

    // ---- stage W_src image: 2048 x 16B units, 4 per thread, linear ----
#pragma unroll
    for (int jj = 0; jj < 4; ++jj) {
        int unit = jj * 512 + tid;
        gload_lds16(Wimg + (size_t)unit * 8, &Ws[unit * 8]);
    }
    asm volatile("" ::: "memory");

    // ---- issue src gathers (compiler has drained idx for addressing) ----
    const short* ps = xb + (size_t)si * D128;
    bf16x8 bs[4];
#pragma unroll
    for (int ks = 0; ks < 4; ++ks)
        bs[ks] = *reinterpret_cast<const bf16x8*>(ps + ks * 32 + lhi * 8);
    asm volatile("" ::: "memory");
    asm volatile("s_waitcnt vmcnt(4)" ::: "memory");   // drain stage; bs fly
    __builtin_amdgcn_s_barrier();

    f32x4 acc[8];
#pragma unroll
    for (int mt = 0; mt < 8; ++mt) acc[mt] = (f32x4){0.f, 0.f, 0.f, 0.f};

    // ---- phase 1: MFMA src; prefetch dst gathers ----
    const short* pd = xb + (size_t)di * D128;
    bf16x8 bd[4];
#pragma unroll
    for (int ks = 0; ks < 4; ++ks)
        bd[ks] = *reinterpret_cast<const bf16x8*>(pd + ks * 32 + lhi * 8);
    asm volatile("" ::: "memory");
#pragma unroll
    for (int ks = 0; ks < 4; ++ks)
#pragma unroll
        for (int mt = 0; mt < 8; ++mt) {
            bf16x8 a = *reinterpret_cast<const bf16x8*>(
                &Ws[((mt * 4 + ks) * 64 + lane) * 8]);
            acc[mt] = __builtin_amdgcn_mfma_f32_16x16x32_bf16(a, bs[ks], acc[mt], 0, 0, 0);
        }
    __builtin_amdgcn_s_barrier();          // all waves done reading Ws (src)

    // ---- restage: W_dst image ----
#pragma unroll
    for (int jj = 0; jj < 4; ++jj) {
        int unit = jj * 512 + tid;
        gload_lds16(Wimg + (size_t)(IMG_SHORTS + unit * 8), &Ws[unit * 8]);
    }
    asm volatile("" ::: "memory");
    asm volatile("s_waitcnt vmcnt(0)" ::: "memory");   // drain bd + stage
    __builtin_amdgcn_s_barrier();

    // ---- phase 2: MFMA dst; prefetch e rows (fp32) ----
    const float* pe = e + (size_t)rn * D128;
    float4 ev[8];
#pragma unroll
    for (int ks = 0; ks < 4; ++ks) {
        ev[2 * ks]     = reinterpret_cast<const float4*>(pe + ks * 32 + lhi * 8)[0];
        ev[2 * ks + 1] = reinterpret_cast<const float4*>(pe + ks * 32 + lhi * 8)[1];
    }
    asm volatile("" ::: "memory");
#pragma unroll
    for (int ks = 0; ks < 4; ++ks)
#pragma unroll
        for (int mt = 0; mt < 8; ++mt) {
            bf16x8 a = *reinterpret_cast<const bf16x8*>(
                &Ws[((mt * 4 + ks) * 64 + lane) * 8]);
            acc[mt] = __builtin_amdgcn_mfma_f32_16x16x32_bf16(a, bd[ks], acc[mt], 0, 0, 0);
        }
    __builtin_amdgcn_s_barrier();          // all waves done reading Ws (dst)

    // ---- restage: W_e image ----
#pragma unroll
    for (int jj = 0; jj < 4; ++jj) {
        int unit = jj * 512 + tid;
        gload_lds16(Wimg + (size_t)(2 * IMG_SHORTS + unit * 8), &Ws[unit * 8]);
    }
    asm volatile("" ::: "memory");
    asm volatile("s_waitcnt vmcnt(0)" ::: "memory");   // drain ev + stage
    __builtin_amdgcn_s_barrier();

    // ---- phase 3: pack e, MFMA e ----
    bf16x8 be[4];
#pragma unroll
    for (int ks = 0; ks < 4; ++ks) be[ks] = pack8(ev[2 * ks], ev[2 * ks + 1]);
#pragma unroll
    for (int ks = 0; ks < 4; ++ks)
#pragma unroll
        for (int mt = 0; mt < 8; ++mt) {
            bf16x8 a = *reinterpret_cast<const bf16x8*>(
                &Ws[((mt * 4 + ks) * 64 + lane) * 8]);
            acc[mt] = __builtin_amdgcn_mfma_f32_16x16x32_bf16(a, be[ks], acc[mt], 0, 0, 0);
        }

    // ---- epilogue: lane holds out[rn][mt*16 + lhi*4 .. +3] -> dwordx4 ----
    float* po = out + (size_t)rn * D128 + lhi * 4;
#pragma unroll
    for (int mt = 0; mt < 8; ++mt)
        *reinterpret_cast<float4*>(po + mt * 16) = *(float4*)&acc[mt];
}

extern "C" void kernel_launch(void* const* d_in, const int* in_sizes, int n_in,
                              void* d_out, int out_size, void* d_ws, size_t ws_size,
                              hipStream_t stream) {
    const float* x = (const float*)d_in[0];
    const float* e = (const float*)d_in[1];
    const float* W = (const float*)d_in[2];
    const int* src = (const int*)d_in[3];
    const int* dst = (const int*)d_in[4];
    float* out = (float*)d_out;

    short* Wimg = (short*)d_ws;                 // 3 x 32 KB frag images
    short* xb   = (short*)d_ws + XB_OFF;        // 100000*128 bf16 = 25.6 MB

    const int N = in_sizes[0] / D128;           // 100000
    const int E = in_sizes[3];                  // 400000

    wt_kernel<<<24, 256, 0, stream>>>(W, Wimg);
    xb_kernel<<<(N * D128) / (256 * 8), 256, 0, stream>>>(x, xb);
    fused_kernel<<<E / D128, 512, 0, stream>>>(xb, e, Wimg, src, dst, out);
}